// Round 2
// baseline (11675.937 us; speedup 1.0000x reference)
//
#include <hip/hip_runtime.h>
#include <cstdint>
#include <cstddef>

// Problem constants
#define SENC  128
#define NSTEPS 159          // 128 encoder + 31 decoder
#define HB    524288        // elements per h buffer (512*1024)
#define SLAB_ELEMS 55296    // per-c weight slab: 36*3*64*8 shorts
#define FRAG_TOTAL 442368   // 64*36*3*64 fragment slots

typedef short  short8  __attribute__((ext_vector_type(8)));
typedef float  floatx4 __attribute__((ext_vector_type(4)));
typedef float  f32x4   __attribute__((ext_vector_type(4)));

#define MFMA(a, b, c) __builtin_amdgcn_mfma_f32_16x16x32_bf16((a), (b), (c), 0, 0, 0)

// ---------- bf16 helpers (RNE) ----------
__device__ __forceinline__ float bf2f(short s) {
    return __uint_as_float(((unsigned)(unsigned short)s) << 16);
}
__device__ __forceinline__ short f2bf(float f) {
    unsigned u = __float_as_uint(f);
    return (short)((u + 0x7FFFu + ((u >> 16) & 1u)) >> 16);
}
__device__ __forceinline__ void f2pair(float f, short& hi, short& lo) {
    hi = f2bf(f);
    lo = f2bf(f - bf2f(hi));
}
__device__ __forceinline__ void cvt8(const float* __restrict__ src, short8& hi, short8& lo) {
    f32x4 a = ((const f32x4*)src)[0];
    f32x4 b = ((const f32x4*)src)[1];
    float f[8];
#pragma unroll
    for (int j = 0; j < 4; ++j) { f[j] = a[j]; f[4 + j] = b[j]; }
#pragma unroll
    for (int j = 0; j < 8; ++j) {
        short h, l;
        f2pair(f[j], h, l);
        hi[j] = h; lo[j] = l;
    }
}

__device__ __forceinline__ float sigm(float x) {
    return 1.0f / (1.0f + __expf(-x));
}
__device__ __forceinline__ float tanh_fast(float x) {
    float cx = fminf(fmaxf(x, -15.0f), 15.0f);
    float e = __expf(2.0f * cx);
    return (e - 1.0f) / (e + 1.0f);
}

// ---------- r-group barrier (64 blocks, sense via monotone generation) ----------
__device__ __forceinline__ void rbar(unsigned* cnt, unsigned* gen) {
    __syncthreads();
    if (threadIdx.x == 0) {
        __threadfence();   // release: drain + wb L2 so our h/ps writes are device-visible
        unsigned g   = __hip_atomic_load(gen, __ATOMIC_RELAXED, __HIP_MEMORY_SCOPE_AGENT);
        unsigned old = __hip_atomic_fetch_add(cnt, 1u, __ATOMIC_RELAXED, __HIP_MEMORY_SCOPE_AGENT);
        if (old == (g + 1u) * 64u - 1u) {
            __hip_atomic_store(gen, g + 1u, __ATOMIC_RELAXED, __HIP_MEMORY_SCOPE_AGENT);
        } else {
            while (__hip_atomic_load(gen, __ATOMIC_RELAXED, __HIP_MEMORY_SCOPE_AGENT) <= g)
                __builtin_amdgcn_s_sleep(1);
        }
        __threadfence();   // acquire: inv L1/L2 so we see peers' h/ps
    }
    __syncthreads();
}

// ---------- setup: swizzle [Wi|Wh] into MFMA B-fragment order, hi/lo split ----------
__global__ void setup_swizzle(const float* __restrict__ Wi, const float* __restrict__ Wh,
                              short* __restrict__ whi, short* __restrict__ wlo) {
    const int idx = blockIdx.x * 256 + threadIdx.x;
    if (idx >= FRAG_TOTAL) return;
    const int l    = idx & 63;
    const int rest = idx >> 6;
    const int t    = rest % 3;
    const int ki   = (rest / 3) % 36;
    const int c    = rest / 108;
    const int nrow = t * 1024 + c * 16 + (l & 15);
    const int kb   = ki * 32 + (l >> 4) * 8;
    short8 vh, vl;
#pragma unroll
    for (int j = 0; j < 8; ++j) {
        const int k = kb + j;
        float w = (k < 128) ? Wi[(size_t)nrow * 128 + k]
                            : Wh[(size_t)nrow * 1024 + (k - 128)];
        short h, lo2;
        f2pair(w, h, lo2);
        vh[j] = h; vl[j] = lo2;
    }
    *(short8*)(whi + (size_t)idx * 8) = vh;
    *(short8*)(wlo + (size_t)idx * 8) = vl;
}

// ---------- region-2 prefetch bundle ----------
struct PF { short8 l0, l1, l2, ah, al; };

__device__ __forceinline__ PF pf_load(const short* __restrict__ wlo_c,
                                      const short* __restrict__ hbh,
                                      const short* __restrict__ hbl,
                                      int ki, int lane, int brow) {
    PF p;
    const int fo = ((ki * 3) * 64 + lane) * 8;
    p.l0 = *(const short8*)(wlo_c + fo);
    p.l1 = *(const short8*)(wlo_c + fo + 512);
    p.l2 = *(const short8*)(wlo_c + fo + 1024);
    const int hk = (ki - 4) * 32 + ((lane >> 4) * 8);
    p.ah = *(const short8*)(hbh + (size_t)brow * 1024 + hk);
    p.al = *(const short8*)(hbl + (size_t)brow * 1024 + hk);
    return p;
}

__device__ __forceinline__ void do_ki(const PF& p, const short* s_whi, int ki, int lane,
                                      floatx4& aR, floatx4& aZ, floatx4& aNh) {
    const int fo = ((ki * 3) * 64 + lane) * 8;
    short8 b0 = *(const short8*)(s_whi + fo);
    short8 b1 = *(const short8*)(s_whi + fo + 512);
    short8 b2 = *(const short8*)(s_whi + fo + 1024);
    aR  = MFMA(p.ah, b0, aR);  aR  = MFMA(p.ah, p.l0, aR);  aR  = MFMA(p.al, b0, aR);
    aZ  = MFMA(p.ah, b1, aZ);  aZ  = MFMA(p.ah, p.l1, aZ);  aZ  = MFMA(p.al, b1, aZ);
    aNh = MFMA(p.ah, b2, aNh); aNh = MFMA(p.ah, p.l2, aNh); aNh = MFMA(p.al, b2, aNh);
}

// ---------- main persistent cooperative kernel ----------
__global__ __launch_bounds__(512, 2) void gru_main(
    const float* __restrict__ feats, const float* __restrict__ labels,
    const float* __restrict__ bi,    const float* __restrict__ bh,
    const float* __restrict__ Wd,    const float* __restrict__ bd,
    const short* __restrict__ whi_sw, const short* __restrict__ wlo_sw,
    short* __restrict__ h_hi, short* __restrict__ h_lo,
    float* __restrict__ ps_f32, float* __restrict__ out,
    unsigned* __restrict__ bar_cnt, unsigned* __restrict__ bar_gen)
{
    __shared__ short s_whi[SLAB_ELEMS];   // 108 KB resident W_hi slab (fragment order)

    const int tid  = threadIdx.x;
    const int lane = tid & 63;
    const int wv   = tid >> 6;            // wave 0..7
    const int q    = lane >> 4;
    const int n16  = lane & 15;
    const int c    = blockIdx.x & 63;     // out-group: h-cols [16c, 16c+16)
    const int r    = blockIdx.x >> 6;     // batch-group: rows [128r, 128r+128)

    // stage W_hi slab
    {
        const f32x4* src = (const f32x4*)(whi_sw + (size_t)c * SLAB_ELEMS);
        f32x4* dst = (f32x4*)s_whi;
        for (int i = tid; i < SLAB_ELEMS / 8; i += 512) dst[i] = src[i];
    }
    __syncthreads();

    const int mbase = r * 128 + wv * 16;  // this wave's 16 batch rows
    const int brow  = mbase + n16;        // A-fragment row for this lane
    const int row_r = c * 16 + n16;       // gate row (within each gate part) == D col
    const float bias_r  = bi[row_r] + bh[row_r];
    const float bias_z  = bi[1024 + row_r] + bh[1024 + row_r];
    const float bias_ni = bi[2048 + row_r];
    const float bias_nh = bh[2048 + row_r];
    const int hcol = row_r;
    const short* wlo_c = wlo_sw + (size_t)c * SLAB_ELEMS;

    unsigned* cnt = bar_cnt + r;
    unsigned* gen = bar_gen + r;

    // hoist region-1 W_lo fragments (step-invariant): 12 x short8 = 48 VGPRs
    short8 L0[4], L1[4], L2[4];
#pragma unroll
    for (int ki = 0; ki < 4; ++ki) {
        const int fo = ((ki * 3) * 64 + lane) * 8;
        L0[ki] = *(const short8*)(wlo_c + fo);
        L1[ki] = *(const short8*)(wlo_c + fo + 512);
        L2[ki] = *(const short8*)(wlo_c + fo + 1024);
    }

    float hold[4] = {0.f, 0.f, 0.f, 0.f};  // h carried in-register (lane owns (b,hcol))

    for (int step = 0; step < NSTEPS; ++step) {
        const int  cur = step & 1, nxt = cur ^ 1;
        const bool dec = (step >= SENC);
        const int  t   = dec ? step - SENC : step;

        floatx4 aR  = (floatx4){bias_r,  bias_r,  bias_r,  bias_r};
        floatx4 aZ  = (floatx4){bias_z,  bias_z,  bias_z,  bias_z};
        floatx4 aNi = (floatx4){bias_ni, bias_ni, bias_ni, bias_ni};
        floatx4 aNh = (floatx4){bias_nh, bias_nh, bias_nh, bias_nh};

        const short* hbh = h_hi + (size_t)cur * HB;
        const short* hbl = h_lo + (size_t)cur * HB;

        // ---- region 2 first (h part, k 128..1151): depth-2 register pipeline ----
        {
            PF f0 = pf_load(wlo_c, hbh, hbl, 4, lane, brow);
            PF f1 = pf_load(wlo_c, hbh, hbl, 5, lane, brow);
#pragma unroll
            for (int ki = 4; ki < 36; ki += 2) {
                PF c0 = f0;
                if (ki + 2 < 36) f0 = pf_load(wlo_c, hbh, hbl, ki + 2, lane, brow);
                do_ki(c0, s_whi, ki, lane, aR, aZ, aNh);
                PF c1 = f1;
                if (ki + 3 < 36) f1 = pf_load(wlo_c, hbh, hbl, ki + 3, lane, brow);
                do_ki(c1, s_whi, ki + 1, lane, aR, aZ, aNh);
            }
        }

        // ---- region 1: x part (k 0..127), fp32 sources, hoisted W_lo ----
#pragma unroll
        for (int ki = 0; ki < 4; ++ki) {
            const int fo = ((ki * 3) * 64 + lane) * 8;
            short8 b0 = *(const short8*)(s_whi + fo);
            short8 b1 = *(const short8*)(s_whi + fo + 512);
            short8 b2 = *(const short8*)(s_whi + fo + 1024);
            const float* src;
            if (ki < 2)      src = feats  + ((size_t)brow * 159 + step) * 64 + ki * 32 + q * 8;
            else if (!dec)   src = labels + ((size_t)brow * 128 + t) * 64 + (ki - 2) * 32 + q * 8;
            else             src = ps_f32 + (size_t)brow * 64 + (ki - 2) * 32 + q * 8;
            short8 ah, al;
            cvt8(src, ah, al);
            aR  = MFMA(ah, b0, aR);  aR  = MFMA(ah, L0[ki], aR);  aR  = MFMA(al, b0, aR);
            aZ  = MFMA(ah, b1, aZ);  aZ  = MFMA(ah, L1[ki], aZ);  aZ  = MFMA(al, b1, aZ);
            aNi = MFMA(ah, b2, aNi); aNi = MFMA(ah, L2[ki], aNi); aNi = MFMA(al, b2, aNi);
        }

        // ---- epilogue: GRU update, h_old in registers, write pair to nxt buffer ----
        {
            short* nhh = h_hi + (size_t)nxt * HB;
            short* nhl = h_lo + (size_t)nxt * HB;
#pragma unroll
            for (int i = 0; i < 4; ++i) {
                const int b = mbase + q * 4 + i;     // D row = (lane>>4)*4 + reg
                float rr = sigm(aR[i]);
                float zz = sigm(aZ[i]);
                float nn = tanh_fast(aNi[i] + rr * aNh[i]);
                float hv = (1.0f - zz) * nn + zz * hold[i];
                hold[i] = hv;
                short sh, sl;
                f2pair(hv, sh, sl);
                const size_t idx = (size_t)b * 1024 + hcol;
                nhh[idx] = sh;
                nhl[idx] = sl;
            }
        }
        rbar(cnt, gen);   // publish h within r-group

        // ---- ps phase: after encoder (step 127) and every decoder step ----
        if (step >= SENC - 1) {
            const int ot  = step - (SENC - 1);       // output time 0..31
            const int hb2 = (step + 1) & 1;
            const short* hh = h_hi + (size_t)hb2 * HB;
            const short* hl = h_lo + (size_t)hb2 * HB;
            const int dot  = tid >> 2;               // 0..127: 2 rows x 64 outs
            const int quar = tid & 3;                // K-slice of 256
            const int prow = r * 128 + 2 * c + (dot >> 6);
            const int o    = dot & 63;
            const float* wrow = Wd + (size_t)o * 1024 + quar * 256;
            const short* hrh  = hh + (size_t)prow * 1024 + quar * 256;
            const short* hrl  = hl + (size_t)prow * 1024 + quar * 256;
            float acc = 0.0f;
#pragma unroll 8
            for (int k = 0; k < 256; k += 4) {
                const unsigned* ph = (const unsigned*)(hrh + k);
                const unsigned* pl = (const unsigned*)(hrl + k);
                unsigned a0 = ph[0], a1 = ph[1], c0 = pl[0], c1 = pl[1];
                f32x4 w = *(const f32x4*)(wrow + k);
                acc += (__uint_as_float(a0 << 16)         + __uint_as_float(c0 << 16))         * w[0];
                acc += (__uint_as_float(a0 & 0xFFFF0000u) + __uint_as_float(c0 & 0xFFFF0000u)) * w[1];
                acc += (__uint_as_float(a1 << 16)         + __uint_as_float(c1 << 16))         * w[2];
                acc += (__uint_as_float(a1 & 0xFFFF0000u) + __uint_as_float(c1 & 0xFFFF0000u)) * w[3];
            }
            acc += __shfl_xor(acc, 1);
            acc += __shfl_xor(acc, 2);
            if (quar == 0) {
                float v = acc + bd[o];
                out[((size_t)ot * 512 + prow) * 64 + o] = v;
                ps_f32[(size_t)prow * 64 + o] = v;
            }
            rbar(cnt, gen);   // publish ps within r-group
        }
    }
}

extern "C" void kernel_launch(void* const* d_in, const int* in_sizes, int n_in,
                              void* d_out, int out_size, void* d_ws, size_t ws_size,
                              hipStream_t stream) {
    const float* feats  = (const float*)d_in[0];
    const float* labels = (const float*)d_in[1];
    const float* Wi     = (const float*)d_in[2];
    const float* Wh     = (const float*)d_in[3];
    const float* bi     = (const float*)d_in[4];
    const float* bh     = (const float*)d_in[5];
    const float* Wd     = (const float*)d_in[6];
    const float* bd     = (const float*)d_in[7];
    float* out = (float*)d_out;

    char* ws = (char*)d_ws;
    short* whi_sw = (short*)(ws);                       // 7,077,888 B
    short* wlo_sw = (short*)(ws + 7077888);             // 7,077,888 B
    short* h_hi   = (short*)(ws + 14155776);            // 2,097,152 B (2 buffers)
    short* h_lo   = (short*)(ws + 16252928);            // 2,097,152 B
    float* ps_f32 = (float*)(ws + 18350080);            //   131,072 B
    unsigned* bar_cnt = (unsigned*)(ws + 18481152);     //        16 B (4 r-groups)
    unsigned* bar_gen = (unsigned*)(ws + 18481168);     //        16 B

    // zero h buffer 0 (buffer 1 is written before first read) and barrier state
    hipMemsetAsync(h_hi, 0, 1048576, stream);
    hipMemsetAsync(h_lo, 0, 1048576, stream);
    hipMemsetAsync(bar_cnt, 0, 32, stream);

    setup_swizzle<<<FRAG_TOTAL / 256, 256, 0, stream>>>(Wi, Wh, whi_sw, wlo_sw);

    void* args[] = {(void*)&feats, (void*)&labels, (void*)&bi, (void*)&bh,
                    (void*)&Wd, (void*)&bd, (void*)&whi_sw, (void*)&wlo_sw,
                    (void*)&h_hi, (void*)&h_lo, (void*)&ps_f32, (void*)&out,
                    (void*)&bar_cnt, (void*)&bar_gen};
    hipLaunchCooperativeKernel(reinterpret_cast<void*>(gru_main),
                               dim3(256), dim3(512), args, 0, stream);
}